// Round 7
// baseline (133.061 us; speedup 1.0000x reference)
//
#include <hip/hip_runtime.h>

#define VOCAB 10000
#define EMB   16
#define HID   32
#define BATCH 4096
#define TLEN  512

// ---------------------------------------------------------------------------
// Kernel 1: P[v][j] = b[j] + sum_e emb[v][e] * Wx[e][j]   (fp32 table in ws)
// ---------------------------------------------------------------------------
__global__ __launch_bounds__(256) void rnn_proj(
    const float* __restrict__ emb, const float* __restrict__ Wx,
    const float* __restrict__ bias, float* __restrict__ P)
{
    int tid = blockIdx.x * 256 + threadIdx.x;
    if (tid >= VOCAB * HID) return;
    int v = tid >> 5;
    int j = tid & 31;
    float acc = bias[j];
    const float* ev = emb + v * EMB;
#pragma unroll
    for (int e = 0; e < EMB; ++e) {
        acc = fmaf(ev[e], Wx[e * HID + j], acc);
    }
    P[tid] = acc;
}

// ---------------------------------------------------------------------------
// Kernel 2: K-split scan. ONE batch per wave (4096 waves = 4/SIMD, double
// r6's occupancy to hide the ~250cy serial chain). Lane = (j = lane&31,
// khalf = lane>>5). Each lane does a HALF dot product (16 FMAs over k-range
// khalf*16..+16); halves combined with one __shfl_xor(part, 32).
// Per wave-step: 4 ds_read_b128 (vs 8) + 16 FMA (vs 32) + tanh.
// h lives in a wave-private LDS row (no barriers ever).
// ---------------------------------------------------------------------------
__global__ __launch_bounds__(256)
__attribute__((amdgpu_waves_per_eu(4)))
void rnn_scan(
    const int*   __restrict__ x,   const float* __restrict__ P,
    const float* __restrict__ Wh,  const float* __restrict__ Wd,
    const float* __restrict__ bd,  float* __restrict__ out)
{
    __shared__ float h_lds[4][HID];             // 1 row per wave, 512 B

    const int lane = threadIdx.x & 63;
    const int wave = threadIdx.x >> 6;
    const int j    = lane & 31;
    const int kh   = lane >> 5;                 // which 16-wide k-half
    const int b    = blockIdx.x * 4 + wave;

    // 16 weights: Wh[kh*16 + s][j]
    float w[16];
#pragma unroll
    for (int s = 0; s < 16; ++s) w[s] = Wh[(kh * 16 + s) * HID + j];

    h_lds[wave][j] = 0.0f;                      // h0 = 0 (both halves write same)

    const int* xb = x + b * TLEN;

    // software pipeline: pA = P(t), pB = P(t+1), tok2 = token(t+2)
    int   tok2 = xb[2];
    float pA = P[xb[0] * HID + j];
    float pB = P[xb[1] * HID + j];

    float hj = 0.0f;
    const float TWO_LOG2E = 2.8853900817779268f; // 2*log2(e)
    const float4* hrow = (const float4*)(&h_lds[wave][0]) + kh * 4;

    for (int t = 0; t < TLEN; ++t) {
        // prefetch token(t+3); issue P(t+2) with token loaded last iteration
        int   ti   = (t + 3 < TLEN) ? (t + 3) : (TLEN - 1);
        int   tok3 = xb[ti];
        float pC   = P[tok2 * HID + j];

        // half dot: sum_{s in khalf} h[kh*16+s] * Wh[kh*16+s][j]
        float a0 = 0.f, a1 = 0.f, a2 = 0.f, a3 = 0.f;
#pragma unroll
        for (int q = 0; q < 4; ++q) {
            float4 hv = hrow[q];
            a0 = fmaf(hv.x, w[4 * q + 0], a0);
            a1 = fmaf(hv.y, w[4 * q + 1], a1);
            a2 = fmaf(hv.z, w[4 * q + 2], a2);
            a3 = fmaf(hv.w, w[4 * q + 3], a3);
        }
        float part = (a0 + a1) + (a2 + a3);

        // combine the two k-halves (partner lane = lane ^ 32)
        part += __shfl_xor(part, 32, 64);
        float z = pA + part;

        // tanh(z) = 1 - 2/(e^{2z}+1); saturates cleanly (inf -> 1, 0 -> -1)
        float e2 = __builtin_amdgcn_exp2f(z * TWO_LOG2E);
        float r  = __builtin_amdgcn_rcpf(e2 + 1.0f);
        hj = fmaf(-2.0f, r, 1.0f);

        h_lds[wave][j] = hj;                    // both halves write same value

        pA = pB; pB = pC; tok2 = tok3;
    }

    // out[b] = sigmoid(sum_j h_j * Wd[j] + bd)
    float s = hj * Wd[j];
#pragma unroll
    for (int off = 16; off > 0; off >>= 1)
        s += __shfl_xor(s, off, 32);            // reduce within 32-lane group
    if (lane == 0) {
        float logit = s + bd[0];
        out[b] = 1.0f / (1.0f + __expf(-logit)); // fp32 output
    }
}

// ---------------------------------------------------------------------------
extern "C" void kernel_launch(void* const* d_in, const int* in_sizes, int n_in,
                              void* d_out, int out_size, void* d_ws, size_t ws_size,
                              hipStream_t stream)
{
    const int*   x   = (const int*)  d_in[0];
    const float* emb = (const float*)d_in[1];
    const float* Wx  = (const float*)d_in[2];
    const float* Wh  = (const float*)d_in[3];
    const float* bia = (const float*)d_in[4];
    const float* Wd  = (const float*)d_in[5];
    const float* bd  = (const float*)d_in[6];
    float* out = (float*)d_out;

    float* P = (float*)d_ws;                    // VOCAB*HID*4 = 1.28 MB

    rnn_proj<<<(VOCAB * HID + 255) / 256, 256, 0, stream>>>(emb, Wx, bia, P);
    rnn_scan<<<BATCH / 4, 256, 0, stream>>>(x, P, Wh, Wd, bd, out);
}